// Round 5
// baseline (170.368 us; speedup 1.0000x reference)
//
#include <hip/hip_runtime.h>
#include <hip/hip_bf16.h>
#include <stdint.h>

// Problem constants: N=16384, M=1024, D=1024, fp32 in/out
#define NN 16384
#define MM 1024
#define DD 1024

typedef __attribute__((ext_vector_type(4))) int   int4v;
typedef __attribute__((ext_vector_type(8))) int   int8v;   // 8 dwords = 32 fp8 (MX MFMA A/B frag)
typedef __attribute__((ext_vector_type(4))) float f4;      // MFMA C/D frag

// pack 4 fp32 -> 4 OCP e4m3 bytes in a dword (HW RNE)
__device__ __forceinline__ uint32_t pk4fp8(float a, float b, float c, float d) {
    uint32_t lo = __builtin_amdgcn_cvt_pk_fp8_f32(a, b, 0, false);
    return __builtin_amdgcn_cvt_pk_fp8_f32(c, d, lo, true);
}

// async global->LDS, 16B per lane; LDS dest is wave-uniform base + lane*16
__device__ __forceinline__ void async16(const void* g, void* l) {
    __builtin_amdgcn_global_load_lds(
        (const __attribute__((address_space(1))) void*)g,
        (__attribute__((address_space(3))) void*)l, 16, 0, 0);
}

// ---- fused row squared-norms (fp32) + fp32->fp8 convert: one wave per row ----
__global__ __launch_bounds__(256)
void rowsq_cvt8(const float* __restrict__ x, float* __restrict__ sq,
                uint32_t* __restrict__ x8, int rows, int cols) {
    int row  = (blockIdx.x * 256 + threadIdx.x) >> 6;
    int lane = threadIdx.x & 63;
    if (row >= rows) return;
    const f4* p  = (const f4*)(x + (size_t)row * cols);
    uint32_t* ob = x8 + (size_t)row * (cols / 4);
    float s = 0.f;
    int nf4 = cols >> 2;
    for (int i = lane; i < nf4; i += 64) {
        f4 v = p[i];
        s = fmaf(v.x, v.x, s); s = fmaf(v.y, v.y, s);
        s = fmaf(v.z, v.z, s); s = fmaf(v.w, v.w, s);
        ob[i] = pk4fp8(v.x, v.y, v.z, v.w);
    }
#pragma unroll
    for (int off = 32; off > 0; off >>= 1) s += __shfl_down(s, off);
    if (lane == 0) sq[row] = s;
}

// ---- fp32 [k][c] -> fp8 [c][k] transpose+convert (norm) ----
__global__ __launch_bounds__(256)
void trcvt8(const float* __restrict__ in, uint8_t* __restrict__ out) {
    __shared__ float t[32][33];
    int tx = threadIdx.x & 31, ty = threadIdx.x >> 5;  // 32 x 8
    int bx = blockIdx.x, by = blockIdx.y;
#pragma unroll
    for (int i = 0; i < 32; i += 8)
        t[ty + i][tx] = in[(size_t)(by * 32 + ty + i) * MM + bx * 32 + tx];
    __syncthreads();
    int c  = threadIdx.x >> 3;        // 0..31
    int rg = (threadIdx.x & 7) * 4;   // 0,4,...,28
    uint32_t u = pk4fp8(t[rg + 0][c], t[rg + 1][c], t[rg + 2][c], t[rg + 3][c]);
    *(uint32_t*)&out[(size_t)(bx * 32 + c) * MM + by * 32 + rg] = u;
}

// ---- MX-fp8 MFMA GEMM: 128x128 tile, BK=128, DOUBLE-BUFFERED LDS ----
// Round-4 K-loop exposed full load latency every iter (issue -> immediate
// vmcnt(0) drain at barrier). Now: barrier drains tile i (issued one full
// compute-section ago), then tile i+1 is issued and flies while tile i's
// MFMAs run. One barrier per iter. LDS 2x32KB -> 2 blocks/CU; intra-block
// pipelining replaces the lost co-residency.
constexpr int BM = 128, BN = 128, BK = 128;

__device__ __forceinline__ void stage_tile(
    const uint8_t* __restrict__ A, const uint8_t* __restrict__ Bt,
    uint8_t* sA, uint8_t* sB, int brow, int bcol, int kt,
    int wave, int srow, int schk)
{
#pragma unroll
    for (int i = 0; i < 4; ++i) {
        int rb = wave * 32 + i * 8;
        const uint8_t* ga = A  + (size_t)(brow + rb + srow) * 1024 + kt + schk * 16;
        async16(ga, &sA[rb * BK]);
        const uint8_t* gb = Bt + (size_t)(bcol + rb + srow) * 1024 + kt + schk * 16;
        async16(gb, &sB[rb * BK]);
    }
}

template<bool EXP_EPI>
__global__ __launch_bounds__(256)
void mfma_gemm_fp8(const uint8_t* __restrict__ A, const uint8_t* __restrict__ Bt,
                   void* __restrict__ Cv, const float* __restrict__ xsq,
                   const float* __restrict__ csq, const float* __restrict__ gamma_p)
{
    constexpr int K = 1024, NC = 1024, NIT = K / BK;
    __shared__ __align__(16) uint8_t sA[2][BM * BK];  // 2 x 16 KB
    __shared__ __align__(16) uint8_t sB[2][BN * BK];  // 2 x 16 KB

    const int tid  = threadIdx.x;
    const int lane = tid & 63;
    const int wave = tid >> 6;        // 0..3
    const int q    = lane >> 4;       // k-quarter
    const int l15  = lane & 15;
    const int wm   = (wave >> 1) * 64;
    const int wn   = (wave & 1) * 64;

    // XCD swizzle (round-3 verified: FETCH 264->33 MB): xcd = bid&7; each XCD
    // owns 16 consecutive row-panels; col-blocks of a panel back-to-back.
    const int bid  = blockIdx.y * gridDim.x + blockIdx.x;   // 0..1023
    const int xcd  = bid & 7;
    const int slot = bid >> 3;
    const int bx   = slot & 7;
    const int by   = (xcd << 4) | (slot >> 3);
    const int brow = by * BM;
    const int bcol = bx * BN;

    // staging source coords: 1 async16 covers 8 rows x 128B; 16B chunks are
    // XOR-swizzled by row&7 on the source side (bank-conflict fix, round 4)
    const int srow = lane >> 3;
    const int schk = (lane & 7) ^ (srow & 7);

    // prefetch epilogue scalar early (hides ~600cyc load behind the K-loop)
    const float gam = EXP_EPI ? gamma_p[0] : 0.f;

    f4 acc[4][4];
#pragma unroll
    for (int i = 0; i < 4; ++i)
#pragma unroll
        for (int j = 0; j < 4; ++j)
            acc[i][j] = (f4){0.f, 0.f, 0.f, 0.f};

    // prologue: stage tile 0 into buffer 0
    stage_tile(A, Bt, sA[0], sB[0], brow, bcol, 0, wave, srow, schk);

#pragma unroll
    for (int it = 0; it < NIT; ++it) {
        const int cur = it & 1;
        __syncthreads();  // drains tile `it`'s asyncs (vmcnt 0) + joins waves
        if (it + 1 < NIT)  // issue next tile; flies during this iter's compute
            stage_tile(A, Bt, sA[cur ^ 1], sB[cur ^ 1],
                       brow, bcol, (it + 1) * BK, wave, srow, schk);

        int8v a[4], b[4];
#pragma unroll
        for (int mi = 0; mi < 4; ++mi) {
            int row = wm + mi * 16 + l15;
            const uint8_t* base = &sA[cur][row * BK];
            int4v lo = *(const int4v*)(base + (((2 * q)     ^ (row & 7)) * 16));
            int4v hi = *(const int4v*)(base + (((2 * q + 1) ^ (row & 7)) * 16));
            a[mi] = __builtin_shufflevector(lo, hi, 0, 1, 2, 3, 4, 5, 6, 7);
        }
#pragma unroll
        for (int ni = 0; ni < 4; ++ni) {
            int col = wn + ni * 16 + l15;
            const uint8_t* base = &sB[cur][col * BK];
            int4v lo = *(const int4v*)(base + (((2 * q)     ^ (col & 7)) * 16));
            int4v hi = *(const int4v*)(base + (((2 * q + 1) ^ (col & 7)) * 16));
            b[ni] = __builtin_shufflevector(lo, hi, 0, 1, 2, 3, 4, 5, 6, 7);
        }
#pragma unroll
        for (int mi = 0; mi < 4; ++mi)
#pragma unroll
            for (int ni = 0; ni < 4; ++ni)
                acc[mi][ni] = __builtin_amdgcn_mfma_scale_f32_16x16x128_f8f6f4(
                    a[mi], b[ni], acc[mi][ni],
                    0, 0,                 // cbsz=FP8(e4m3), blgp=FP8(e4m3)
                    0, 0x7F7F7F7F,        // scale_a = 1.0 (e8m0 bias 127)
                    0, 0x7F7F7F7F);       // scale_b = 1.0
    }

    // C/D layout (shape-determined, 16x16): col = lane&15, row = quad*4 + reg
    if constexpr (EXP_EPI) {
        uint8_t* C = (uint8_t*)Cv;
        float cs[4];
#pragma unroll
        for (int ni = 0; ni < 4; ++ni) cs[ni] = csq[bcol + wn + ni * 16 + l15];
#pragma unroll
        for (int mi = 0; mi < 4; ++mi) {
#pragma unroll
            for (int r = 0; r < 4; ++r) {
                int row = brow + wm + mi * 16 + q * 4 + r;
                float xs = xsq[row];
#pragma unroll
                for (int ni = 0; ni < 4; ++ni) {
                    int col = bcol + wn + ni * 16 + l15;
                    float sq = xs + cs[ni] - 2.0f * acc[mi][ni][r];
                    float d = __expf(-gam * sq);  // underflows to 0 (sq ~>1500)
                    C[(size_t)row * NC + col] =
                        (uint8_t)(__builtin_amdgcn_cvt_pk_fp8_f32(d, d, 0, false) & 0xFF);
                }
            }
        }
    } else {
        float* C = (float*)Cv;
#pragma unroll
        for (int mi = 0; mi < 4; ++mi)
#pragma unroll
            for (int r = 0; r < 4; ++r) {
                int row = brow + wm + mi * 16 + q * 4 + r;
#pragma unroll
                for (int ni = 0; ni < 4; ++ni)
                    C[(size_t)row * NC + bcol + wn + ni * 16 + l15] = acc[mi][ni][r];
            }
    }
}

extern "C" void kernel_launch(void* const* d_in, const int* in_sizes, int n_in,
                              void* d_out, int out_size, void* d_ws, size_t ws_size,
                              hipStream_t stream) {
    const float* inputs  = (const float*)d_in[0];   // [N, D]
    const float* centers = (const float*)d_in[1];   // [M, D]
    const float* gamma   = (const float*)d_in[2];   // [1]
    const float* norm    = (const float*)d_in[3];   // [M, M]
    float* out = (float*)d_out;                     // [N, M]

    // ws layout: xsq 64K | csq 4K | c8 1M | n8 1M | dens8 16M  (~18.1 MiB)
    char* w = (char*)d_ws;
    float*   xsq   = (float*)w;
    float*   csq   = (float*)(w + 65536);
    uint8_t* c8    = (uint8_t*)(w + 69632);
    uint8_t* n8    = (uint8_t*)(w + 69632 + (1u << 20));
    uint8_t* dens8 = (uint8_t*)(w + 69632 + (2u << 20));
    // x in fp8 parked in d_out (16 of its 64 MiB): dead before stage 2 writes.
    uint32_t* x8   = (uint32_t*)d_out;

    rowsq_cvt8<<<NN / 4, 256, 0, stream>>>(inputs,  xsq, x8, NN, DD);
    rowsq_cvt8<<<MM / 4, 256, 0, stream>>>(centers, csq, (uint32_t*)c8, MM, DD);
    trcvt8<<<dim3(32, 32), 256, 0, stream>>>(norm, n8);

    dim3 grid(MM / BN, NN / BM);  // (8, 128), XCD-swizzled in-kernel
    // stage 1: dens = exp(-g * (xsq + csq - 2 * x @ centers^T)), fp8 out
    mfma_gemm_fp8<true><<<grid, 256, 0, stream>>>(
        (const uint8_t*)x8, c8, dens8, xsq, csq, gamma);
    // stage 2: out = dens @ norm (via norm^T), fp32 out
    mfma_gemm_fp8<false><<<grid, 256, 0, stream>>>(
        dens8, n8, out, nullptr, nullptr, nullptr);
}

// Round 6
// 163.992 us; speedup vs baseline: 1.0389x; 1.0389x over previous
//
#include <hip/hip_runtime.h>
#include <hip/hip_bf16.h>
#include <stdint.h>

// Problem constants: N=16384, M=1024, D=1024, fp32 in/out
#define NN 16384
#define MM 1024
#define DD 1024

typedef __attribute__((ext_vector_type(4)))  int   int4v;
typedef __attribute__((ext_vector_type(8)))  int   int8v;   // 32 fp8 (MX MFMA A/B frag)
typedef __attribute__((ext_vector_type(4)))  float f4;
typedef __attribute__((ext_vector_type(16))) float f16v;    // 32x32 MFMA C/D frag

// pack 4 fp32 -> 4 OCP e4m3 bytes in a dword (HW RNE)
__device__ __forceinline__ uint32_t pk4fp8(float a, float b, float c, float d) {
    uint32_t lo = __builtin_amdgcn_cvt_pk_fp8_f32(a, b, 0, false);
    return __builtin_amdgcn_cvt_pk_fp8_f32(c, d, lo, true);
}

// ---- fused row squared-norms (fp32) + fp32->fp8 convert: one wave per row ----
__global__ __launch_bounds__(256)
void rowsq_cvt8(const float* __restrict__ x, float* __restrict__ sq,
                uint32_t* __restrict__ x8, int rows, int cols) {
    int row  = (blockIdx.x * 256 + threadIdx.x) >> 6;
    int lane = threadIdx.x & 63;
    if (row >= rows) return;
    const f4* p  = (const f4*)(x + (size_t)row * cols);
    uint32_t* ob = x8 + (size_t)row * (cols / 4);
    float s = 0.f;
    int nf4 = cols >> 2;
    for (int i = lane; i < nf4; i += 64) {
        f4 v = p[i];
        s = fmaf(v.x, v.x, s); s = fmaf(v.y, v.y, s);
        s = fmaf(v.z, v.z, s); s = fmaf(v.w, v.w, s);
        ob[i] = pk4fp8(v.x, v.y, v.z, v.w);
    }
#pragma unroll
    for (int off = 32; off > 0; off >>= 1) s += __shfl_down(s, off);
    if (lane == 0) sq[row] = s;
}

// ---- fp32 [k][c] -> fp8 [c][k] transpose+convert (norm) ----
__global__ __launch_bounds__(256)
void trcvt8(const float* __restrict__ in, uint8_t* __restrict__ out) {
    __shared__ float t[32][33];
    int tx = threadIdx.x & 31, ty = threadIdx.x >> 5;  // 32 x 8
    int bx = blockIdx.x, by = blockIdx.y;
#pragma unroll
    for (int i = 0; i < 32; i += 8)
        t[ty + i][tx] = in[(size_t)(by * 32 + ty + i) * MM + bx * 32 + tx];
    __syncthreads();
    int c  = threadIdx.x >> 3;        // 0..31
    int rg = (threadIdx.x & 7) * 4;   // 0,4,...,28
    uint32_t u = pk4fp8(t[rg + 0][c], t[rg + 1][c], t[rg + 2][c], t[rg + 3][c]);
    *(uint32_t*)&out[(size_t)(bx * 32 + c) * MM + by * 32 + rg] = u;
}

// ---- MX-fp8 MFMA GEMM, 128x128 tile, BK=128, register-prefetch pipeline ----
// Round-6 changes vs round 4/5:
//  * 32x32x64 MFMA (m59: 4686 TF): half the instrs, HALF the LDS fragment
//    bytes per FLOP (32x32 tiles: 256 B/lane/iter vs 512).
//  * software pipeline: global_load_dwordx4 -> VGPR pf[] issued at top of
//    compute (full MFMA section to fly), ds_write_b128 to LDS next iter.
//    LDS stays 32 KB (single buffer) -> ~3 blocks/CU co-resident (round 5's
//    dbuf halved residency and was neutral; this keeps both).
//  * 16B k-chunks XOR-swizzled by row&7 in LDS (bank-conflict fix, round 4).
// A: [row][k] fp8; Bt: [col][k] fp8. EXP_EPI: C(fp8)=exp(-g*(xsq+csq-2acc));
// else C(fp32)=acc.
constexpr int BM = 128, BN = 128, BK = 128;

template<bool EXP_EPI>
__global__ __launch_bounds__(256)
void mfma_gemm_fp8(const uint8_t* __restrict__ A, const uint8_t* __restrict__ Bt,
                   void* __restrict__ Cv, const float* __restrict__ xsq,
                   const float* __restrict__ csq, const float* __restrict__ gamma_p)
{
    constexpr int K = 1024, NC = 1024, NIT = K / BK;
    __shared__ __align__(16) uint8_t sA[BM * BK];  // 16 KB, sA[r][c16] = G[r][c16 ^ (r&7)]
    __shared__ __align__(16) uint8_t sB[BN * BK];  // 16 KB

    const int tid  = threadIdx.x;
    const int lane = tid & 63;
    const int wave = tid >> 6;        // 0..3
    const int l31  = lane & 31;
    const int kh   = lane >> 5;       // k-half within a k-step
    const int wm   = (wave >> 1) * 64;
    const int wn   = (wave & 1) * 64;

    // XCD swizzle (round-3 verified: FETCH 264->33 MB): xcd = bid&7; each XCD
    // owns 16 consecutive row-panels; col-blocks of a panel back-to-back.
    const int bid  = blockIdx.y * gridDim.x + blockIdx.x;   // 0..1023
    const int xcd  = bid & 7;
    const int slot = bid >> 3;
    const int bx   = slot & 7;
    const int by   = (xcd << 4) | (slot >> 3);
    const int brow = by * BM;
    const int bcol = bx * BN;

    // staging coords: thread covers rows {wave*32 + i*8 + r8}, chunk c8 (16B)
    const int r8 = lane >> 3;         // 0..7
    const int c8 = lane & 7;          // 0..7
    const int wc = c8 ^ r8;           // XOR-swizzled LDS chunk (row&7 == r8)

    const float gam = EXP_EPI ? gamma_p[0] : 0.f;   // hoisted: hides behind K-loop

    f16v acc[2][2];
#pragma unroll
    for (int mi = 0; mi < 2; ++mi)
#pragma unroll
        for (int ni = 0; ni < 2; ++ni)
#pragma unroll
            for (int r = 0; r < 16; ++r) acc[mi][ni][r] = 0.f;

    const uint8_t* ga = A  + (size_t)(brow + wave * 32 + r8) * K + c8 * 16;
    const uint8_t* gb = Bt + (size_t)(bcol + wave * 32 + r8) * K + c8 * 16;
    uint8_t* wa = &sA[(wave * 32 + r8) * BK + wc * 16];
    uint8_t* wb = &sB[(wave * 32 + r8) * BK + wc * 16];

    // prologue: prefetch tile 0 into registers
    int4v pf[8];
#pragma unroll
    for (int i = 0; i < 4; ++i) {
        pf[i]     = *(const int4v*)(ga + (size_t)i * 8 * K);
        pf[4 + i] = *(const int4v*)(gb + (size_t)i * 8 * K);
    }

#pragma unroll
    for (int it = 0; it < NIT; ++it) {
        __syncthreads();              // all waves done reading previous tile
#pragma unroll
        for (int i = 0; i < 4; ++i) { // commit prefetched tile (waits its loads)
            *(int4v*)(wa + i * 8 * BK) = pf[i];
            *(int4v*)(wb + i * 8 * BK) = pf[4 + i];
        }
        __syncthreads();              // tile visible
        if (it + 1 < NIT) {           // issue next tile; flies during MFMAs below
            int koff = (it + 1) * BK;
#pragma unroll
            for (int i = 0; i < 4; ++i) {
                pf[i]     = *(const int4v*)(ga + koff + (size_t)i * 8 * K);
                pf[4 + i] = *(const int4v*)(gb + koff + (size_t)i * 8 * K);
            }
        }
#pragma unroll
        for (int s = 0; s < 2; ++s) { // two 64-deep k-steps per tile
            const int cb = s * 4 + kh * 2;   // 16B-chunk base: k = s*64 + kh*32
            int8v a[2], b[2];
#pragma unroll
            for (int mi = 0; mi < 2; ++mi) {
                int row = wm + mi * 32 + l31;
                const uint8_t* base = &sA[row * BK];
                int4v lo = *(const int4v*)(base + ((cb ^ (row & 7)) * 16));
                int4v hi = *(const int4v*)(base + (((cb + 1) ^ (row & 7)) * 16));
                a[mi] = __builtin_shufflevector(lo, hi, 0, 1, 2, 3, 4, 5, 6, 7);
            }
#pragma unroll
            for (int ni = 0; ni < 2; ++ni) {
                int col = wn + ni * 32 + l31;
                const uint8_t* base = &sB[col * BK];
                int4v lo = *(const int4v*)(base + ((cb ^ (col & 7)) * 16));
                int4v hi = *(const int4v*)(base + (((cb + 1) ^ (col & 7)) * 16));
                b[ni] = __builtin_shufflevector(lo, hi, 0, 1, 2, 3, 4, 5, 6, 7);
            }
#pragma unroll
            for (int mi = 0; mi < 2; ++mi)
#pragma unroll
                for (int ni = 0; ni < 2; ++ni)
                    acc[mi][ni] = __builtin_amdgcn_mfma_scale_f32_32x32x64_f8f6f4(
                        a[mi], b[ni], acc[mi][ni],
                        0, 0,                 // cbsz/blgp = FP8 e4m3
                        0, 0x7F7F7F7F,        // scale_a = 1.0 (e8m0 127)
                        0, 0x7F7F7F7F);       // scale_b = 1.0
        }
    }

    // C/D layout (32x32, m74/m101-verified, dtype-independent):
    //   col = lane&31, row = (reg&3) + 8*(reg>>2) + 4*(lane>>5)
    if constexpr (EXP_EPI) {
        uint8_t* C = (uint8_t*)Cv;
        float cs[2];
        cs[0] = csq[bcol + wn + l31];
        cs[1] = csq[bcol + wn + 32 + l31];
#pragma unroll
        for (int mi = 0; mi < 2; ++mi)
#pragma unroll
            for (int r = 0; r < 16; ++r) {
                int rl  = (r & 3) + 8 * (r >> 2) + 4 * kh;
                int row = brow + wm + mi * 32 + rl;
                float xs = xsq[row];
#pragma unroll
                for (int ni = 0; ni < 2; ++ni) {
                    int col = bcol + wn + ni * 32 + l31;
                    float sq = xs + cs[ni] - 2.0f * acc[mi][ni][r];
                    float d = __expf(-gam * sq);  // underflows to 0 (sq ~>1500)
                    C[(size_t)row * NC + col] =
                        (uint8_t)(__builtin_amdgcn_cvt_pk_fp8_f32(d, d, 0, false) & 0xFF);
                }
            }
    } else {
        float* C = (float*)Cv;
#pragma unroll
        for (int mi = 0; mi < 2; ++mi)
#pragma unroll
            for (int r = 0; r < 16; ++r) {
                int rl  = (r & 3) + 8 * (r >> 2) + 4 * kh;
                int row = brow + wm + mi * 32 + rl;
#pragma unroll
                for (int ni = 0; ni < 2; ++ni)
                    C[(size_t)row * NC + bcol + wn + ni * 32 + l31] = acc[mi][ni][r];
            }
    }
}

extern "C" void kernel_launch(void* const* d_in, const int* in_sizes, int n_in,
                              void* d_out, int out_size, void* d_ws, size_t ws_size,
                              hipStream_t stream) {
    const float* inputs  = (const float*)d_in[0];   // [N, D]
    const float* centers = (const float*)d_in[1];   // [M, D]
    const float* gamma   = (const float*)d_in[2];   // [1]
    const float* norm    = (const float*)d_in[3];   // [M, M]
    float* out = (float*)d_out;                     // [N, M]

    // ws layout: xsq 64K | csq 4K | c8 1M | n8 1M | dens8 16M  (~18.1 MiB)
    char* w = (char*)d_ws;
    float*   xsq   = (float*)w;
    float*   csq   = (float*)(w + 65536);
    uint8_t* c8    = (uint8_t*)(w + 69632);
    uint8_t* n8    = (uint8_t*)(w + 69632 + (1u << 20));
    uint8_t* dens8 = (uint8_t*)(w + 69632 + (2u << 20));
    // x in fp8 parked in d_out (16 of its 64 MiB): dead before stage 2 writes.
    uint32_t* x8   = (uint32_t*)d_out;

    rowsq_cvt8<<<NN / 4, 256, 0, stream>>>(inputs,  xsq, x8, NN, DD);
    rowsq_cvt8<<<MM / 4, 256, 0, stream>>>(centers, csq, (uint32_t*)c8, MM, DD);
    trcvt8<<<dim3(32, 32), 256, 0, stream>>>(norm, n8);

    dim3 grid(MM / BN, NN / BM);  // (8, 128), XCD-swizzled in-kernel
    // stage 1: dens = exp(-g * (xsq + csq - 2 * x @ centers^T)), fp8 out
    mfma_gemm_fp8<true><<<grid, 256, 0, stream>>>(
        (const uint8_t*)x8, c8, dens8, xsq, csq, gamma);
    // stage 2: out = dens @ norm (via norm^T), fp32 out
    mfma_gemm_fp8<false><<<grid, 256, 0, stream>>>(
        dens8, n8, out, nullptr, nullptr, nullptr);
}